// Round 4
// baseline (225.349 us; speedup 1.0000x reference)
//
#include <hip/hip_runtime.h>

// Tree-LSTM AST encoder, complete 8-ary tree, N=100000, D=128, C=8.
// Internal nodes 0..12499, leaves 12500..99999 (result == emb row), sentinel 100000.
// Levels (deepest first): L5 [4681,12500) | L4 [585,4681) | L3 [73,585)
//                         L2 [9,73) | L1 [1,9) | L0 [0,1)  -- L1+L0 fused (1 block).
//
// 8-wave blocks. Wave w owns dims w*16..w*16+15 for all 4 gates; LSTM cell fully
// in registers from MFMA C/D frags (col=lane&15, row=(lane>>4)*4+reg).
// Weights: 32 B-frags (128 VGPR)/wave, loaded once per block straight from fp32 W.
// Single barrier per step via double-buffered Xh; child x prefetched 2-3 steps
// ahead into registers (gather latency hidden under MFMA).
//
// ws: resultsH f16[12500*128] (3.2 MB)

#define D 128
#define NTOT 100000
#define NINT 12500

typedef _Float16 f16x8 __attribute__((ext_vector_type(8)));
typedef _Float16 f16x4 __attribute__((ext_vector_type(4)));
typedef float    f32x4 __attribute__((ext_vector_type(4)));

__device__ __forceinline__ float fsig(float x) {
    return __builtin_amdgcn_rcpf(1.f + __expf(-x));        // x->-inf: rcp(inf)=0 ok
}
__device__ __forceinline__ float ftanh(float x) {
    return 1.f - 2.f * __builtin_amdgcn_rcpf(__expf(2.f * x) + 1.f);  // inf-safe, NaN-free
}

template<int DPT> struct XVT;
template<> struct XVT<8> { using T = f16x8; };
template<> struct XVT<4> { using T = f16x4; };

template<int RT, bool FUSE_ROOT>
__global__ __launch_bounds__(512, 2) void lstm_level(
    int start, int count,
    const float* __restrict__ emb, const int* __restrict__ node_types,
    const int* __restrict__ children,
    const float* __restrict__ W_ih, const float* __restrict__ W_hh,
    const float* __restrict__ b_ih, const float* __restrict__ b_hh,
    _Float16* __restrict__ resultsH, float* __restrict__ out)
{
    constexpr int NR  = 16 * RT;
    constexpr int TPR = 512 / NR;
    constexpr int DPT = 128 / TPR;
    using xvec = typename XVT<DPT>::T;

    __shared__ __align__(16) _Float16 Xh[2][NR][264];   // [buf][node][ x(128) | h(128) | pad ]
    __shared__ int      chid_s[NR][8];
    __shared__ __align__(16) _Float16 Hstash[8][128];   // FUSE: L1 results for root pass

    const int t  = threadIdx.x;
    const int w  = t >> 6;
    const int l  = t & 63;
    const int n0 = start + (int)blockIdx.x * NR;
    const int B  = min(NR, start + count - n0);

    const int row = t / TPR;             // gather row
    const int di  = (t % TPR) * DPT;     // gather dim offset
    const int dcol = w * 16 + (l & 15);  // cell/output dim

    // ---- stage child ids ----
    if (t < NR * 8) {
        int rr = t >> 3, slot = t & 7;
        chid_s[rr][slot] = children[(size_t)(n0 + rr) * 8 + slot];
    }
    __syncthreads();

    // ---- weights straight from fp32 W, in B-fragment order (reg-resident) ----
    f16x8 bf[4][8];
#pragma unroll
    for (int ct = 0; ct < 4; ++ct) {
        const int c = ct * 128 + dcol;
#pragma unroll
        for (int kk = 0; kk < 8; ++kk) {
            const int k0 = (kk & 3) * 32 + ((l >> 4) * 8);
            const float* src = (kk < 4) ? (W_ih + (size_t)c * D + k0)
                                        : (W_hh + (size_t)c * D + k0);
            float4 a = *(const float4*)(src);
            float4 b = *(const float4*)(src + 4);
            f16x8 v;
            v[0]=(_Float16)a.x; v[1]=(_Float16)a.y; v[2]=(_Float16)a.z; v[3]=(_Float16)a.w;
            v[4]=(_Float16)b.x; v[5]=(_Float16)b.y; v[6]=(_Float16)b.z; v[7]=(_Float16)b.w;
            bf[ct][kk] = v;
        }
    }
    float4 bb;
    bb.x = b_ih[dcol      ] + b_hh[dcol      ];
    bb.y = b_ih[dcol + 128] + b_hh[dcol + 128];
    bb.z = b_ih[dcol + 256] + b_hh[dcol + 256];
    bb.w = b_ih[dcol + 384] + b_hh[dcol + 384];

    // ---- per-thread activity bitmask for my cell rows (bit s = step s active) ----
    unsigned amask[RT][4];
#pragma unroll
    for (int rt = 0; rt < RT; ++rt)
#pragma unroll
        for (int r = 0; r < 4; ++r) {
            const int r2 = rt * 16 + ((l >> 4) * 4) + r;
            unsigned m = 1u;
#pragma unroll
            for (int slot = 0; slot < 8; ++slot)
                m |= (chid_s[r2][slot] < NTOT ? 1u : 0u) << (slot + 1);
            amask[rt][r] = m;
        }

    // ---- gather issue helper (x_s for my (row,di)) ----
    auto issue_gather = [&](int s) -> xvec {
        xvec v = (xvec)(_Float16)0.f;
        const float*    srcF = nullptr;
        const _Float16* srcH = nullptr;
        if (s == 0) {
            srcF = emb + (size_t)node_types[n0 + row] * D + di;
        } else {
            int ch = chid_s[row][s - 1];
            if (ch < NINT)      srcH = resultsH + (size_t)ch * D + di;
            else if (ch < NTOT) srcF = emb + (size_t)node_types[ch] * D + di;
        }
        if (srcH) {
            v = *(const xvec*)srcH;
        } else if (srcF) {
#pragma unroll
            for (int q = 0; q < DPT; q += 4) {
                float4 a = *(const float4*)(srcF + q);
                v[q+0]=(_Float16)a.x; v[q+1]=(_Float16)a.y;
                v[q+2]=(_Float16)a.z; v[q+3]=(_Float16)a.w;
            }
        }
        return v;
    };

    // ---- prologue: x0 + zero h into buf 0; prefetch x1,x2 ----
    *(xvec*)&Xh[0][row][di]       = issue_gather(0);
    *(xvec*)&Xh[0][row][128 + di] = (xvec)(_Float16)0.f;
    xvec xA = issue_gather(1);
    xvec xB = issue_gather(2);

    float cr[RT][4], hr[RT][4];
#pragma unroll
    for (int rt = 0; rt < RT; ++rt)
#pragma unroll
        for (int r = 0; r < 4; ++r) { cr[rt][r] = 0.f; hr[rt][r] = 0.f; }

    f32x4 acc[RT][4];
    auto mfma_phase = [&](int b) {
#pragma unroll
        for (int rt = 0; rt < RT; ++rt)
#pragma unroll
            for (int ct = 0; ct < 4; ++ct) acc[rt][ct] = (f32x4){0.f, 0.f, 0.f, 0.f};
#pragma unroll
        for (int kk = 0; kk < 8; ++kk) {
#pragma unroll
            for (int rt = 0; rt < RT; ++rt) {
                f16x8 a = *(const f16x8*)&Xh[b][rt * 16 + (l & 15)][kk * 32 + ((l >> 4) * 8)];
#pragma unroll
                for (int ct = 0; ct < 4; ++ct)
                    acc[rt][ct] = __builtin_amdgcn_mfma_f32_16x16x32_f16(a, bf[ct][kk], acc[rt][ct], 0, 0, 0);
            }
        }
    };
    auto cell_phase = [&](int s, int b, bool always) {
#pragma unroll
        for (int rt = 0; rt < RT; ++rt)
#pragma unroll
            for (int r = 0; r < 4; ++r) {
                const int r2 = rt * 16 + ((l >> 4) * 4) + r;
                const bool upd = always || ((amask[rt][r] >> s) & 1u);
                if (upd) {
                    float iv = fsig (acc[rt][0][r] + bb.x);
                    float fv = fsig (acc[rt][1][r] + bb.y);
                    float gv = ftanh(acc[rt][2][r] + bb.z);
                    float ov = fsig (acc[rt][3][r] + bb.w);
                    float cn = fv * cr[rt][r] + iv * gv;
                    cr[rt][r] = cn;
                    hr[rt][r] = ov * ftanh(cn);
                }
                if (s < 8) Xh[b ^ 1][r2][128 + dcol] = (_Float16)hr[rt][r];
            }
    };

    __syncthreads();

    // ---- main 9-step pass, one barrier per step ----
    for (int s = 0; s < 9; ++s) {
        const int b = s & 1;
        mfma_phase(b);
        if (s < 8) {
            *(xvec*)&Xh[b ^ 1][row][di] = xA;   // x_{s+1} (prefetched 2 steps ago)
            xA = xB;
            if (s <= 5) xB = issue_gather(s + 3);
        }
        cell_phase(s, b, false);
        __syncthreads();
    }

    // ---- epilogue ----
#pragma unroll
    for (int rt = 0; rt < RT; ++rt)
#pragma unroll
        for (int r = 0; r < 4; ++r) {
            const int r2 = rt * 16 + ((l >> 4) * 4) + r;
            if (r2 < B) {
                resultsH[(size_t)(n0 + r2) * D + dcol] = (_Float16)hr[rt][r];
                if (FUSE_ROOT && r2 < 8) Hstash[r2][dcol] = (_Float16)hr[rt][r];
            }
        }

    // ---- fused root pass: node 0, children = nodes 1..8 (in Hstash) ----
    if constexpr (FUSE_ROOT) {
        __syncthreads();   // Hstash visible; pass-1 reads of Xh all done
        {
            const int nt0 = node_types[0];
            xvec v0;
#pragma unroll
            for (int q = 0; q < DPT; q += 4) {
                float4 a = *(const float4*)(emb + (size_t)nt0 * D + di + q);
                v0[q+0]=(_Float16)a.x; v0[q+1]=(_Float16)a.y;
                v0[q+2]=(_Float16)a.z; v0[q+3]=(_Float16)a.w;
            }
            *(xvec*)&Xh[0][row][di]       = v0;
            *(xvec*)&Xh[0][row][128 + di] = (xvec)(_Float16)0.f;
        }
#pragma unroll
        for (int rt = 0; rt < RT; ++rt)
#pragma unroll
            for (int r = 0; r < 4; ++r) { cr[rt][r] = 0.f; hr[rt][r] = 0.f; }
        __syncthreads();

        for (int s = 0; s < 9; ++s) {
            const int b = s & 1;
            mfma_phase(b);
            if (s < 8) {
                xvec v = *(const xvec*)&Hstash[s][di];   // child s of node 0 = node s+1
                *(xvec*)&Xh[b ^ 1][row][di] = v;
            }
            cell_phase(s, b, true);
            __syncthreads();
        }
        // row 0 holds node 0: lanes with (l>>4)==0 carry r2==0 at r==0
        if ((l >> 4) == 0) out[dcol] = hr[0][0];
    }
}

extern "C" void kernel_launch(void* const* d_in, const int* in_sizes, int n_in,
                              void* d_out, int out_size, void* d_ws, size_t ws_size,
                              hipStream_t stream)
{
    const float* emb        = (const float*)d_in[0];
    const float* W_ih       = (const float*)d_in[1];
    const float* W_hh       = (const float*)d_in[2];
    const float* b_ih       = (const float*)d_in[3];
    const float* b_hh       = (const float*)d_in[4];
    const int*   node_types = (const int*)d_in[5];
    const int*   children   = (const int*)d_in[6];

    float*    out      = (float*)d_out;
    _Float16* resultsH = (_Float16*)d_ws;    // 3.2 MB

    lstm_level<2,false><<<245, 512, 0, stream>>>(4681, 7819, emb, node_types, children,
                                                 W_ih, W_hh, b_ih, b_hh, resultsH, out);
    lstm_level<1,false><<<256, 512, 0, stream>>>(585, 4096, emb, node_types, children,
                                                 W_ih, W_hh, b_ih, b_hh, resultsH, out);
    lstm_level<1,false><<<32, 512, 0, stream>>>(73, 512, emb, node_types, children,
                                                W_ih, W_hh, b_ih, b_hh, resultsH, out);
    lstm_level<1,false><<<4, 512, 0, stream>>>(9, 64, emb, node_types, children,
                                               W_ih, W_hh, b_ih, b_hh, resultsH, out);
    lstm_level<1,true><<<1, 512, 0, stream>>>(1, 8, emb, node_types, children,
                                              W_ih, W_hh, b_ih, b_hh, resultsH, out);
}

// Round 5
// 106.229 us; speedup vs baseline: 2.1214x; 2.1214x over previous
//
#include <hip/hip_runtime.h>

// Tree-LSTM AST encoder, complete 8-ary tree, N=100000, D=128, C=8.
// Internal nodes 0..12499, leaves 12500..99999 (result == emb row), sentinel 100000.
// Levels (deepest first): L5 [4681,12500) | L4 [585,4681) | L3 [73,585)
//                         L2 [9,73) | L1 [1,9) | L0 [0,1)  -- L1+L0 fused (1 block).
//
// 8-wave (512-thr) blocks, __launch_bounds__(512) only: 8-wave block forces
// 2 waves/SIMD -> 256-VGPR cap; kernel needs ~204 -> NO SPILL (R4's regression
// was launch_bounds(512,2) => 128-VGPR cap => 50MB/dispatch scratch traffic).
// Wave w owns dims w*16..w*16+15 for all 4 gates; LSTM cell fully in registers
// from MFMA C/D frags (col=lane&15, row=(lane>>4)*4+reg). Weights: 32 B-frags
// (128 regs)/wave loaded once from pre-packed f16 wfrag (AGPR-parkable).
// All gathers (leaf emb + internal results) are direct f16 vector loads via a
// pre-converted embH table -> 2-step register prefetch truly hides latency.
// Double-buffered Xh: ONE barrier per step.
//
// ws: resultsH f16[12500*128] (3.2MB) | wfrag f16[131072] (256KB)
//     | bias4 float4[128] (2KB) | embH f16[131*128] (33.5KB)

#define D 128
#define NTOT 100000
#define NINT 12500
#define NTYPES 131

typedef _Float16 f16x8 __attribute__((ext_vector_type(8)));
typedef _Float16 f16x4 __attribute__((ext_vector_type(4)));
typedef float    f32x4 __attribute__((ext_vector_type(4)));

__device__ __forceinline__ float fsig(float x) {
    return __builtin_amdgcn_rcpf(1.f + __expf(-x));
}
__device__ __forceinline__ float ftanh(float x) {
    return 1.f - 2.f * __builtin_amdgcn_rcpf(__expf(2.f * x) + 1.f);
}

template<int DPT> struct XVT;
template<> struct XVT<8> { using T = f16x8; };
template<> struct XVT<4> { using T = f16x4; };

// Pack weights into per-(wave,gate,ktile,lane) f16 B-fragments, fuse biases,
// and convert the embedding table to f16.
//   frag half index (((w*4+ct)*8+kk)*64 + l)*8 + j  holds  Wcat[k][c]:
//     k = (kk&3)*32 + (l>>4)*8 + j, src = kk<4 ? W_ih : W_hh
//     c = ct*128 + w*16 + (l&15);  B[k][c] = W[c][k]
__global__ void prep(const float* __restrict__ W_ih, const float* __restrict__ W_hh,
                     const float* __restrict__ b_ih, const float* __restrict__ b_hh,
                     const float* __restrict__ emb,
                     _Float16* __restrict__ wfrag, float4* __restrict__ bias4,
                     _Float16* __restrict__ embH)
{
    int t = blockIdx.x * blockDim.x + threadIdx.x;   // 16896 threads
    if (t < 8 * 4 * 8 * 64) {
        int l  = t & 63;
        int kk = (t >> 6) & 7;
        int ct = (t >> 9) & 3;
        int w  = (t >> 11) & 7;
        int k0 = (kk & 3) * 32 + ((l >> 4) * 8);
        int c  = ct * 128 + w * 16 + (l & 15);
        const float* src = (kk < 4) ? (W_ih + (size_t)c * D + k0)
                                    : (W_hh + (size_t)c * D + k0);
        f16x8 v;
#pragma unroll
        for (int j = 0; j < 8; ++j) v[j] = (_Float16)src[j];
        *(f16x8*)(wfrag + (size_t)t * 8) = v;
    }
    if (t < D) {
        bias4[t] = make_float4(b_ih[t      ] + b_hh[t      ],
                               b_ih[t + 128] + b_hh[t + 128],
                               b_ih[t + 256] + b_hh[t + 256],
                               b_ih[t + 384] + b_hh[t + 384]);
    }
    if (t < NTYPES * D / 8) {
        f16x8 v;
#pragma unroll
        for (int j = 0; j < 8; ++j) v[j] = (_Float16)emb[t * 8 + j];
        *(f16x8*)(embH + (size_t)t * 8) = v;
    }
}

template<int RT, bool FUSE_ROOT>
__global__ __launch_bounds__(512) void lstm_level(
    int start, int count,
    const _Float16* __restrict__ embH, const int* __restrict__ node_types,
    const int* __restrict__ children,
    const _Float16* __restrict__ wfrag, const float4* __restrict__ bias4,
    _Float16* __restrict__ resultsH, float* __restrict__ out)
{
    constexpr int NR  = 16 * RT;
    constexpr int TPR = 512 / NR;
    constexpr int DPT = 128 / TPR;
    using xvec = typename XVT<DPT>::T;

    __shared__ __align__(16) _Float16 Xh[2][NR][264];   // [buf][node][ x(128)|h(128)|pad ]
    __shared__ int chid_s[NR][8];
    __shared__ int chty_s[NR][8];
    __shared__ __align__(16) _Float16 Hstash[8][128];

    const int t  = threadIdx.x;
    const int w  = t >> 6;
    const int l  = t & 63;
    const int n0 = start + (int)blockIdx.x * NR;
    const int B  = min(NR, start + count - n0);

    const int row  = t / TPR;
    const int di   = (t % TPR) * DPT;
    const int dcol = w * 16 + (l & 15);

    // ---- stage child ids + leaf-child types ----
    if (t < NR * 8) {
        int rr = t >> 3, slot = t & 7;
        int ch = children[(size_t)(n0 + rr) * 8 + slot];
        chid_s[rr][slot] = ch;
        chty_s[rr][slot] = (ch >= NINT && ch < NTOT) ? node_types[ch] : 0;
    }

    // ---- weights: 32 clean 16B loads -> B-fragments (AGPR-parkable) ----
    f16x8 bf[4][8];
#pragma unroll
    for (int ct = 0; ct < 4; ++ct)
#pragma unroll
        for (int kk = 0; kk < 8; ++kk)
            bf[ct][kk] = *(const f16x8*)(wfrag + ((size_t)(((w * 4 + ct) * 8 + kk) * 64 + l)) * 8);
    const float4 bb = bias4[dcol];

    __syncthreads();   // chid_s/chty_s visible

    auto issue_gather = [&](int s) -> xvec {
        const _Float16* src;
        if (s == 0) {
            src = embH + (size_t)node_types[n0 + row] * D + di;
        } else {
            int ch = chid_s[row][s - 1];
            if (ch >= NTOT) return (xvec)(_Float16)0.f;
            src = (ch < NINT) ? (resultsH + (size_t)ch * D + di)
                              : (embH + (size_t)chty_s[row][s - 1] * D + di);
        }
        return *(const xvec*)src;
    };

    // ---- prologue: x0 + zero h into buf0; prefetch x1,x2 ----
    *(xvec*)&Xh[0][row][di]       = issue_gather(0);
    *(xvec*)&Xh[0][row][128 + di] = (xvec)(_Float16)0.f;
    xvec xA = issue_gather(1);
    xvec xB = issue_gather(2);

    float cr[RT][4], hr[RT][4];
#pragma unroll
    for (int rt = 0; rt < RT; ++rt)
#pragma unroll
        for (int r = 0; r < 4; ++r) { cr[rt][r] = 0.f; hr[rt][r] = 0.f; }

    f32x4 acc[RT][4];
    auto mfma_phase = [&](int b) {
#pragma unroll
        for (int rt = 0; rt < RT; ++rt)
#pragma unroll
            for (int ct = 0; ct < 4; ++ct) acc[rt][ct] = (f32x4){0.f, 0.f, 0.f, 0.f};
#pragma unroll
        for (int kk = 0; kk < 8; ++kk) {
#pragma unroll
            for (int rt = 0; rt < RT; ++rt) {
                f16x8 a = *(const f16x8*)&Xh[b][rt * 16 + (l & 15)][kk * 32 + ((l >> 4) * 8)];
#pragma unroll
                for (int ct = 0; ct < 4; ++ct)
                    acc[rt][ct] = __builtin_amdgcn_mfma_f32_16x16x32_f16(a, bf[ct][kk], acc[rt][ct], 0, 0, 0);
            }
        }
    };
    auto cell_phase = [&](int s, int b, bool always) {
#pragma unroll
        for (int rt = 0; rt < RT; ++rt)
#pragma unroll
            for (int r = 0; r < 4; ++r) {
                const int r2 = rt * 16 + ((l >> 4) * 4) + r;
                const bool upd = always || (s == 0) || (chid_s[r2][s - 1] < NTOT);
                if (upd) {
                    float iv = fsig (acc[rt][0][r] + bb.x);
                    float fv = fsig (acc[rt][1][r] + bb.y);
                    float gv = ftanh(acc[rt][2][r] + bb.z);
                    float ov = fsig (acc[rt][3][r] + bb.w);
                    float cn = fv * cr[rt][r] + iv * gv;
                    cr[rt][r] = cn;
                    hr[rt][r] = ov * ftanh(cn);
                }
                if (s < 8) Xh[b ^ 1][r2][128 + dcol] = (_Float16)hr[rt][r];
            }
    };

    __syncthreads();   // buf0 ready

    for (int s = 0; s < 9; ++s) {
        const int b = s & 1;
        mfma_phase(b);
        if (s < 8) {
            *(xvec*)&Xh[b ^ 1][row][di] = xA;
            xA = xB;
            if (s <= 5) xB = issue_gather(s + 3);
        }
        cell_phase(s, b, false);
        __syncthreads();
    }

    // ---- epilogue ----
#pragma unroll
    for (int rt = 0; rt < RT; ++rt)
#pragma unroll
        for (int r = 0; r < 4; ++r) {
            const int r2 = rt * 16 + ((l >> 4) * 4) + r;
            if (r2 < B) {
                resultsH[(size_t)(n0 + r2) * D + dcol] = (_Float16)hr[rt][r];
                if (FUSE_ROOT && r2 < 8) Hstash[r2][dcol] = (_Float16)hr[rt][r];
            }
        }

    // ---- fused root pass: node 0, children 1..8 live in Hstash ----
    if constexpr (FUSE_ROOT) {
        __syncthreads();
        *(xvec*)&Xh[0][row][di]       = *(const xvec*)(embH + (size_t)node_types[0] * D + di);
        *(xvec*)&Xh[0][row][128 + di] = (xvec)(_Float16)0.f;
#pragma unroll
        for (int rt = 0; rt < RT; ++rt)
#pragma unroll
            for (int r = 0; r < 4; ++r) { cr[rt][r] = 0.f; hr[rt][r] = 0.f; }
        __syncthreads();

        for (int s = 0; s < 9; ++s) {
            const int b = s & 1;
            mfma_phase(b);
            if (s < 8)
                *(xvec*)&Xh[b ^ 1][row][di] = *(const xvec*)&Hstash[s][di];
            cell_phase(s, b, true);
            __syncthreads();
        }
        if ((l >> 4) == 0) out[dcol] = hr[0][0];
    }
}

extern "C" void kernel_launch(void* const* d_in, const int* in_sizes, int n_in,
                              void* d_out, int out_size, void* d_ws, size_t ws_size,
                              hipStream_t stream)
{
    const float* emb        = (const float*)d_in[0];
    const float* W_ih       = (const float*)d_in[1];
    const float* W_hh       = (const float*)d_in[2];
    const float* b_ih       = (const float*)d_in[3];
    const float* b_hh       = (const float*)d_in[4];
    const int*   node_types = (const int*)d_in[5];
    const int*   children   = (const int*)d_in[6];

    float* out = (float*)d_out;

    char*      ws       = (char*)d_ws;
    _Float16*  resultsH = (_Float16*)ws;                        // 3,200,000 B
    size_t     off      = ((size_t)NINT * D * 2 + 255) & ~(size_t)255;
    _Float16*  wfrag    = (_Float16*)(ws + off);                // 262,144 B
    float4*    bias4    = (float4*)(ws + off + 262144);         // 2,048 B
    _Float16*  embH     = (_Float16*)(ws + off + 262144 + 2048); // 33,536 B

    prep<<<66, 256, 0, stream>>>(W_ih, W_hh, b_ih, b_hh, emb, wfrag, bias4, embH);

    lstm_level<2,false><<<245, 512, 0, stream>>>(4681, 7819, embH, node_types, children,
                                                 wfrag, bias4, resultsH, out);
    lstm_level<1,false><<<256, 512, 0, stream>>>(585, 4096, embH, node_types, children,
                                                 wfrag, bias4, resultsH, out);
    lstm_level<1,false><<<32, 512, 0, stream>>>(73, 512, embH, node_types, children,
                                                wfrag, bias4, resultsH, out);
    lstm_level<1,false><<<4, 512, 0, stream>>>(9, 64, embH, node_types, children,
                                               wfrag, bias4, resultsH, out);
    lstm_level<1,true><<<1, 512, 0, stream>>>(1, 8, embH, node_types, children,
                                              wfrag, bias4, resultsH, out);
}